// Round 22
// baseline (56.067 us; speedup 1.0000x reference)
//
#include <hip/hip_runtime.h>
#include <hip/hip_bf16.h>
#include <math.h>
#include <stdint.h>

#define Bb 16
#define Tt 28
#define Nn 2048
#define Hh 32
#define LAGS 8
#define LN_EPS 1e-5f
#define PSTR 56                      // P row stride (shorts): 2-way banks on b128/b64

typedef float f4 __attribute__((ext_vector_type(4)));
typedef short s8v __attribute__((ext_vector_type(8)));
typedef unsigned short u16x8 __attribute__((ext_vector_type(8)));

__device__ __forceinline__ float b2f(unsigned short u) {
    union { unsigned uu; float ff; } x; x.uu = ((unsigned)u) << 16; return x.ff;
}
__device__ __forceinline__ unsigned short f2b(float f) {
    unsigned u = __float_as_uint(f);
    u += 0x7FFFu + ((u >> 16) & 1u);   // RNE
    return (unsigned short)(u >> 16);
}
__device__ __forceinline__ unsigned packbf2(float lo, float hi) {
    __hip_bfloat162 h = __float22bfloat162_rn(make_float2(lo, hi));
    union { __hip_bfloat162 h2; unsigned u; } c; c.h2 = h; return c.u;
}

// ---------- adj fp32 -> bf16 scaled by geo*5, fragment-tile layout ----------
// adjF[((n>>4)*512 + (m>>2))*64 + (n&15)*4 + (m&3)]
__global__ void k_adjprep(const float* __restrict__ adj, const float* __restrict__ geo_w,
                          unsigned short* __restrict__ adjF) {
    __shared__ float T[16][516];
    float geo = 1.f / (1.f + __expf(-geo_w[0]));
    float cg = geo * 5.f;
    int tid = threadIdx.x;
    int g = blockIdx.x >> 2, q = blockIdx.x & 3;
    int n0 = g * 16, m0 = q * 512;
    #pragma unroll
    for (int r = 0; r < 16; ++r) {
        T[r][tid] = adj[(size_t)(n0 + r) * Nn + m0 + tid];
        T[r][tid + 256] = adj[(size_t)(n0 + r) * Nn + m0 + tid + 256];
    }
    __syncthreads();
    unsigned short* region = adjF + ((size_t)g * 512 + q * 128) * 64;
    #pragma unroll
    for (int i = 0; i < 4; ++i) {
        int e0 = (i * 256 + tid) * 8;
        u16x8 w;
        #pragma unroll
        for (int j = 0; j < 8; ++j) {
            int e = e0 + j;
            int mq = e >> 6, nl = (e >> 2) & 15, mm = e & 3;
            w[j] = f2b(cg * T[nl][mq * 4 + mm]);
        }
        *(u16x8*)(region + e0) = w;
    }
}

// ---------- fused QKV + delayed-signal: Q prescaled by cs; K frag; V 48-row frag ----
// Kf[((b*128+(m>>4))*4+(k>>3))*16+(m&15)][8]        -> 65536 shorts/batch
// Vf[((b*64+(m>>5))*4+((m>>3)&3))*48 + h][8], h<48  -> 98304 shorts/batch
//   rows 0..31 = V^T, row 32 = delayed signal, row 33 = 1.0, rows 34..47 = 0
__global__ void k_qkv(const float* __restrict__ feat, const float* __restrict__ x,
                      const float* __restrict__ dlog,
                      const float* __restrict__ Wq, const float* __restrict__ bq,
                      const float* __restrict__ Wk, const float* __restrict__ bk,
                      const float* __restrict__ Wv, const float* __restrict__ bv,
                      const float* __restrict__ geo_w,
                      unsigned short* __restrict__ Qbf, unsigned short* __restrict__ Kf,
                      unsigned short* __restrict__ Vf) {
    __shared__ float WqT[Hh][Hh + 1], WkT[Hh][Hh + 1], WvT[Hh][Hh + 1];
    __shared__ float f[8][Hh];
    __shared__ __align__(16) unsigned short VT8[Hh][8];
    __shared__ __align__(16) unsigned short DS8[8];
    int tid = threadIdx.x;
    for (int i = tid; i < Hh * Hh; i += 256) {
        int h = i >> 5, k = i & 31;
        WqT[k][h] = Wq[i];
        WkT[k][h] = Wk[i];
        WvT[k][h] = Wv[i];
    }
    int n0 = blockIdx.x * 8;
    int b = n0 >> 11, mloc0 = n0 & 2047;
    // ---- delayed signal for this 8-row octet (wave 0 only) ----
    if (tid < 64) {
        float mx = -1e30f;
        #pragma unroll
        for (int t = 0; t < LAGS; ++t) mx = fmaxf(mx, dlog[t]);
        float s = 0.f, wv[LAGS];
        #pragma unroll
        for (int t = 0; t < LAGS; ++t) { wv[t] = __expf(dlog[t] - mx); s += wv[t]; }
        int t = tid >> 3, j = tid & 7;
        float dsv = (wv[t] / s) * x[(size_t)b * Tt * Nn + (size_t)(Tt - 1 - t) * Nn + mloc0 + j];
        dsv += __shfl_xor(dsv, 8);
        dsv += __shfl_xor(dsv, 16);
        dsv += __shfl_xor(dsv, 32);
        if (tid < 8) DS8[tid] = f2b(dsv);
    }
    float geo = 1.f / (1.f + __expf(-geo_w[0]));
    float cs = (1.f - geo) * 0.17677669529663687f;   // (1-geo)/sqrt(32)
    f[tid >> 5][tid & 31] = feat[(size_t)n0 * Hh + tid];
    __syncthreads();
    int lr = tid >> 5, h = tid & 31;
    float aq = bq[h], ak = bk[h], av = bv[h];
    #pragma unroll
    for (int k = 0; k < Hh; ++k) {
        float fv = f[lr][k];
        aq += fv * WqT[k][h];
        ak += fv * WkT[k][h];
        av += fv * WvT[k][h];
    }
    Qbf[(size_t)(n0 + lr) * Hh + h] = f2b(aq * cs);
    int mloc = mloc0 + lr;
    size_t kaddr = ((((size_t)b * 128 + (mloc >> 4)) * 4 + (h >> 3)) * 16 + (mloc & 15)) * 8 + (h & 7);
    Kf[kaddr] = f2b(ak);
    VT8[h][lr] = f2b(av);
    __syncthreads();
    size_t vbase = (((size_t)b * 64 + (mloc0 >> 5)) * 4 + ((mloc0 >> 3) & 3)) * 48;
    if (tid < 32) {
        *(u16x8*)(Vf + (vbase + tid) * 8) = *(const u16x8*)&VT8[tid][0];
    } else if (tid < 48) {
        int rr = tid - 32;            // 0=ds, 1=ones, 2..15=zero
        u16x8 wv8;
        if (rr == 0) {
            wv8 = *(const u16x8*)&DS8[0];
        } else {
            unsigned short fill = (rr == 1) ? (unsigned short)0x3F80 : (unsigned short)0;
            for (int j = 0; j < 8; ++j) wv8[j] = fill;
        }
        *(u16x8*)(Vf + (vbase + 32 + rr) * 8) = wv8;
    }
}

// ---------------- MFMA attention + fused output-proj + LayerNorm ------------------
// 4 waves/block, 32 n-cols, wave wh owns 32-m quarter of each 128-chunk.
// Software-pipelined P dbuf; pointer-bump loads; sched_barrier(0) pins load issue.
// C-operand built with the dword trick (x<<16 / x&0xFFFF0000) — 4 VALU per tile
// instead of per-element bf16 extraction (issue-bound hypothesis, r21 post-mortem).
// Natural VGPR budget (no min-waves clamp) so both ping-pong Frags can stay live.
__global__ __launch_bounds__(256)
void k_attn(const unsigned short* __restrict__ Qbf,
            const unsigned short* __restrict__ Kf,
            const unsigned short* __restrict__ Vf,
            const unsigned short* __restrict__ adjF,
            const float* __restrict__ feat,
            const float* __restrict__ Wo, const float* __restrict__ bo,
            const float* __restrict__ gamma, const float* __restrict__ beta,
            float* __restrict__ out) {
    __shared__ __align__(16) unsigned short Pt[4][2][32 * PSTR];  // 28672 B; merge scratch later
    __shared__ float WoT[Hh][Hh + 1];
    __shared__ float combT[32][Hh + 1];
    __shared__ float gbb[3][Hh];

    int tid = threadIdx.x;
    int wid = tid >> 6, lane = tid & 63;
    int nl = lane & 15, g4 = lane >> 4;
    int wh = wid;

    for (int i = tid; i < Hh * Hh; i += 256) WoT[i & 31][i >> 5] = Wo[i];
    if (tid < 32) { gbb[0][tid] = bo[tid]; gbb[1][tid] = gamma[tid]; gbb[2][tid] = beta[tid]; }

    // XCD-partitioned swizzle: xcd = bid&7 -> (n-quarter = xcd>>1, batch-half = xcd&1)
    int bid = blockIdx.x;
    int xcd = bid & 7, r = bid >> 3;            // r: 0..127
    int b = ((xcd & 1) << 3) + (r & 7);
    int nt32 = ((xcd >> 1) << 4) + (r >> 3);    // 0..63
    int n0w = nt32 * 32;

    // Q B-fragments (col = n = nl, k = g4*8+j); Q pre-scaled by cs
    s8v qf[2];
    #pragma unroll
    for (int nt = 0; nt < 2; ++nt)
        qf[nt] = *(const s8v*)(Qbf + (((size_t)b * Nn + n0w + nt * 16 + nl) << 5) + g4 * 8);

    f4 pacc[2][3];
    #pragma unroll
    for (int nt = 0; nt < 2; ++nt)
        #pragma unroll
        for (int t = 0; t < 3; ++t) pacc[nt][t] = (f4){0.f, 0.f, 0.f, 0.f};

    const unsigned short* Kb = Kf + (size_t)b * 65536;
    const unsigned short* Vb = Vf + (size_t)b * 98304;
    unsigned short* Pw0 = Pt[wid][0];
    unsigned short* Pw1 = Pt[wid][1];

    // pointer-bump bases (chunk 0, this wave's 32-m window)
    const unsigned short* pK  = Kb + (((size_t)(wh * 2) * 4 + g4) * 16 + nl) * 8;
    const unsigned short* pV  = Vb + (((size_t)wh * 4 + g4) * 48 + nl) * 8;
    const unsigned short* pA0 = adjF + ((size_t)(nt32 * 2) * 512 + wh * 8 + g4) * 64 + nl * 4;
    const unsigned short* pA1 = adjF + ((size_t)(nt32 * 2 + 1) * 512 + wh * 8 + g4) * 64 + nl * 4;

    struct Frag {
        s8v kf0, kf1, vf0, vf1, vf2;
        uint2 a00, a01, a10, a11;
    };

    auto loadP = [&](Frag& F) {
        F.kf0 = *(const s8v*)(pK);
        F.kf1 = *(const s8v*)(pK + 512);
        F.vf0 = *(const s8v*)(pV);
        F.vf1 = *(const s8v*)(pV + 128);
        F.vf2 = *(const s8v*)(pV + 256);
        F.a00 = *(const uint2*)(pA0);
        F.a01 = *(const uint2*)(pA0 + 256);
        F.a10 = *(const uint2*)(pA1);
        F.a11 = *(const uint2*)(pA1 + 256);
        pK += 4096;
        pV += 6144;
        pA0 += 2048;
        pA1 += 2048;
        __builtin_amdgcn_sched_barrier(0);   // pin load issue: no sinking past here
    };

    // C operand from 4 packed bf16 (dword trick: exactly 4 VALU)
    auto mkC = [&](uint2 a) -> f4 {
        f4 C;
        C[0] = __uint_as_float(a.x << 16);
        C[1] = __uint_as_float(a.x & 0xFFFF0000u);
        C[2] = __uint_as_float(a.y << 16);
        C[3] = __uint_as_float(a.y & 0xFFFF0000u);
        return C;
    };

    auto SM = [&](f4 sc, int nt, int mg, unsigned short* Pw) {
        float p0 = __expf(sc[0]), p1 = __expf(sc[1]);
        float p2 = __expf(sc[2]), p3 = __expf(sc[3]);
        uint2 w;
        w.x = packbf2(p0, p1);
        w.y = packbf2(p2, p3);
        *(uint2*)(Pw + (size_t)(nt * 16 + nl) * PSTR + mg * 16 + g4 * 4) = w;
    };

    auto qks = [&](Frag& F, unsigned short* Pw) {
        f4 sc00 = __builtin_amdgcn_mfma_f32_16x16x32_bf16(F.kf0, qf[0], mkC(F.a00), 0, 0, 0);
        f4 sc01 = __builtin_amdgcn_mfma_f32_16x16x32_bf16(F.kf1, qf[0], mkC(F.a01), 0, 0, 0);
        f4 sc10 = __builtin_amdgcn_mfma_f32_16x16x32_bf16(F.kf0, qf[1], mkC(F.a10), 0, 0, 0);
        f4 sc11 = __builtin_amdgcn_mfma_f32_16x16x32_bf16(F.kf1, qf[1], mkC(F.a11), 0, 0, 0);
        SM(sc00, 0, 0, Pw);
        SM(sc01, 0, 1, Pw);
        SM(sc10, 1, 0, Pw);
        SM(sc11, 1, 1, Pw);
    };

    auto readP = [&](const unsigned short* Pw, s8v& pb0, s8v& pb1) {
        pb0 = *(const s8v*)(Pw + (size_t)(0 * 16 + nl) * PSTR + g4 * 8);
        pb1 = *(const s8v*)(Pw + (size_t)(1 * 16 + nl) * PSTR + g4 * 8);
    };

    auto pvm = [&](s8v v0, s8v v1, s8v v2, s8v pb0, s8v pb1) {
        pacc[0][0] = __builtin_amdgcn_mfma_f32_16x16x32_bf16(v0, pb0, pacc[0][0], 0, 0, 0);
        pacc[0][1] = __builtin_amdgcn_mfma_f32_16x16x32_bf16(v1, pb0, pacc[0][1], 0, 0, 0);
        pacc[0][2] = __builtin_amdgcn_mfma_f32_16x16x32_bf16(v2, pb0, pacc[0][2], 0, 0, 0);
        pacc[1][0] = __builtin_amdgcn_mfma_f32_16x16x32_bf16(v0, pb1, pacc[1][0], 0, 0, 0);
        pacc[1][1] = __builtin_amdgcn_mfma_f32_16x16x32_bf16(v1, pb1, pacc[1][1], 0, 0, 0);
        pacc[1][2] = __builtin_amdgcn_mfma_f32_16x16x32_bf16(v2, pb1, pacc[1][2], 0, 0, 0);
    };

    const int NC = Nn / 128;     // 16
    Frag A, B;
    s8v sv0, sv1, sv2, pb0, pb1;

    loadP(A);                    // chunk 0
    loadP(B);                    // chunk 1 (in flight)
    qks(A, Pw0);                 // QK+SM chunk 0 -> P0
    sv0 = A.vf0; sv1 = A.vf1; sv2 = A.vf2;

    for (int i = 0; i < (NC - 2) / 2; ++i) {   // i = 0..6 : chunks 2i+1, 2i+2
        readP(Pw0, pb0, pb1);    // P(2i)  — written a full stage ago
        loadP(A);                // chunk 2i+2 (pinned issue)
        qks(B, Pw1);             // QK+SM chunk 2i+1 -> P(2i+1)
        pvm(sv0, sv1, sv2, pb0, pb1);          // PV chunk 2i
        sv0 = B.vf0; sv1 = B.vf1; sv2 = B.vf2;
        loadP(B);                // chunk 2i+3 (pinned issue)
        readP(Pw1, pb0, pb1);    // P(2i+1)
        qks(A, Pw0);             // QK+SM chunk 2i+2 -> P(2i+2)
        pvm(sv0, sv1, sv2, pb0, pb1);          // PV chunk 2i+1
        sv0 = A.vf0; sv1 = A.vf1; sv2 = A.vf2;
    }
    // epilogue: chunks NC-2 (in A, P in Pw0) and NC-1 (in B)
    readP(Pw0, pb0, pb1);        // P(NC-2)
    qks(B, Pw1);                 // QK+SM chunk NC-1 -> P(NC-1)
    pvm(sv0, sv1, sv2, pb0, pb1);              // PV chunk NC-2
    sv0 = B.vf0; sv1 = B.vf1; sv2 = B.vf2;
    readP(Pw1, pb0, pb1);        // P(NC-1)
    pvm(sv0, sv1, sv2, pb0, pb1);              // PV chunk NC-1

    // ---- linear merge of pacc (24 floats/lane) across the 4 wh waves ----
    float* mrgb = (float*)&Pt[0][0][0];   // 2 regions x 64 lanes x 24 floats = 12288 B <= 28672
    __syncthreads();                      // all PV reads of Pt done
    if (wh & 1) {
        float* d = mrgb + ((size_t)(wh >> 1) * 64 + lane) * 24;
        #pragma unroll
        for (int nt = 0; nt < 2; ++nt)
            #pragma unroll
            for (int t = 0; t < 3; ++t)
                #pragma unroll
                for (int r2 = 0; r2 < 4; ++r2) d[(nt * 3 + t) * 4 + r2] = pacc[nt][t][r2];
    }
    __syncthreads();
    if (!(wh & 1)) {
        const float* d = mrgb + ((size_t)(wh >> 1) * 64 + lane) * 24;
        #pragma unroll
        for (int nt = 0; nt < 2; ++nt)
            #pragma unroll
            for (int t = 0; t < 3; ++t)
                #pragma unroll
                for (int r2 = 0; r2 < 4; ++r2) pacc[nt][t][r2] += d[(nt * 3 + t) * 4 + r2];
    }
    __syncthreads();
    if (wh == 2) {
        float* d = mrgb + (size_t)lane * 24;
        #pragma unroll
        for (int nt = 0; nt < 2; ++nt)
            #pragma unroll
            for (int t = 0; t < 3; ++t)
                #pragma unroll
                for (int r2 = 0; r2 < 4; ++r2) d[(nt * 3 + t) * 4 + r2] = pacc[nt][t][r2];
    }
    __syncthreads();
    if (wh == 0) {
        const float* d = mrgb + (size_t)lane * 24;
        #pragma unroll
        for (int nt = 0; nt < 2; ++nt)
            #pragma unroll
            for (int t = 0; t < 3; ++t)
                #pragma unroll
                for (int r2 = 0; r2 < 4; ++r2) pacc[nt][t][r2] += d[(nt * 3 + t) * 4 + r2];

        // comb = feat + attended/ps + 0.1*prop/ps  -> combT (LDS)
        #pragma unroll
        for (int nt = 0; nt < 2; ++nt) {
            float psn = __shfl(pacc[nt][2][1], nl);   // ones-row (h=33): g4==0, reg 1
            float prn = __shfl(pacc[nt][2][0], nl);   // ds-row   (h=32): g4==0, reg 0
            float invS = 1.f / psn;
            float pp = prn * invS * 0.1f;
            size_t o = ((size_t)b * Nn + n0w + nt * 16 + nl) * Hh;
            #pragma unroll
            for (int t = 0; t < 2; ++t) {
                f4 fv = *(const f4*)(feat + o + t * 16 + g4 * 4);
                #pragma unroll
                for (int r2 = 0; r2 < 4; ++r2)
                    combT[nt * 16 + nl][t * 16 + g4 * 4 + r2] = fv[r2] + pacc[nt][t][r2] * invS + pp;
            }
        }
    }
    __syncthreads();

    // ---- fused output projection + LayerNorm (each wave: 8 rows) ----
    int h = lane & 31;
    #pragma unroll
    for (int pass = 0; pass < 4; ++pass) {
        int row = wh * 8 + pass * 2 + (lane >> 5);
        float a = gbb[0][h];
        #pragma unroll
        for (int k = 0; k < Hh; ++k) a += combT[row][k] * WoT[k][h];
        float mu = a;
        #pragma unroll
        for (int w = 1; w < 32; w <<= 1) mu += __shfl_xor(mu, w);
        mu *= (1.f / 32.f);
        float dd = a - mu;
        float v = dd * dd;
        #pragma unroll
        for (int w = 1; w < 32; w <<= 1) v += __shfl_xor(v, w);
        v *= (1.f / 32.f);
        out[((size_t)b * Nn + n0w + row) * Hh + h] =
            dd * rsqrtf(v + LN_EPS) * gbb[1][h] + gbb[2][h];
    }
}

extern "C" void kernel_launch(void* const* d_in, const int* in_sizes, int n_in,
                              void* d_out, int out_size, void* d_ws, size_t ws_size,
                              hipStream_t stream) {
    const float* x     = (const float*)d_in[0];
    const float* feat  = (const float*)d_in[1];
    const float* dlog  = (const float*)d_in[2];
    const float* Wq    = (const float*)d_in[3];
    const float* bq    = (const float*)d_in[4];
    const float* Wk    = (const float*)d_in[5];
    const float* bk    = (const float*)d_in[6];
    const float* Wv    = (const float*)d_in[7];
    const float* bv    = (const float*)d_in[8];
    const float* adj   = (const float*)d_in[9];
    const float* geo   = (const float*)d_in[10];
    const float* Wo    = (const float*)d_in[11];
    const float* bo    = (const float*)d_in[12];
    const float* gamma = (const float*)d_in[13];
    const float* beta  = (const float*)d_in[14];
    float* out = (float*)d_out;

    char* w = (char*)d_ws;
    unsigned short* Qbf  = (unsigned short*)w;  w += (size_t)Bb * Nn * Hh * 2;
    unsigned short* Kf   = (unsigned short*)w;  w += (size_t)Bb * Nn * Hh * 2;
    unsigned short* Vf   = (unsigned short*)w;  w += (size_t)Bb * 98304 * 2;   // 48-row frag
    unsigned short* adjF = (unsigned short*)w;  w += (size_t)Nn * Nn * 2;

    k_adjprep<<<512, 256, 0, stream>>>(adj, geo, adjF);
    k_qkv<<<Bb * Nn / 8, 256, 0, stream>>>(feat, x, dlog, Wq, bq, Wk, bk, Wv, bv, geo,
                                           Qbf, Kf, Vf);
    k_attn<<<1024, 256, 0, stream>>>(Qbf, Kf, Vf, adjF, feat, Wo, bo, gamma, beta, out);
}

// Round 23
// 53.314 us; speedup vs baseline: 1.0516x; 1.0516x over previous
//
#include <hip/hip_runtime.h>
#include <hip/hip_bf16.h>
#include <math.h>
#include <stdint.h>

#define Bb 16
#define Tt 28
#define Nn 2048
#define Hh 32
#define LAGS 8
#define LN_EPS 1e-5f
#define PSTR 56                      // P row stride (shorts): 2-way banks on b128/b64

typedef float f4 __attribute__((ext_vector_type(4)));
typedef short s8v __attribute__((ext_vector_type(8)));
typedef unsigned short u16x4 __attribute__((ext_vector_type(4)));
typedef unsigned short u16x8 __attribute__((ext_vector_type(8)));

__device__ __forceinline__ float b2f(unsigned short u) {
    union { unsigned uu; float ff; } x; x.uu = ((unsigned)u) << 16; return x.ff;
}
__device__ __forceinline__ unsigned short f2b(float f) {
    unsigned u = __float_as_uint(f);
    u += 0x7FFFu + ((u >> 16) & 1u);   // RNE
    return (unsigned short)(u >> 16);
}
__device__ __forceinline__ unsigned packbf2(float lo, float hi) {
    __hip_bfloat162 h = __float22bfloat162_rn(make_float2(lo, hi));
    union { __hip_bfloat162 h2; unsigned u; } c; c.h2 = h; return c.u;
}

// ---------- adj fp32 -> bf16 scaled by geo*5, fragment-tile layout ----------
// adjF[((n>>4)*512 + (m>>2))*64 + (n&15)*4 + (m&3)]
__global__ void k_adjprep(const float* __restrict__ adj, const float* __restrict__ geo_w,
                          unsigned short* __restrict__ adjF) {
    __shared__ float T[16][516];
    float geo = 1.f / (1.f + __expf(-geo_w[0]));
    float cg = geo * 5.f;
    int tid = threadIdx.x;
    int g = blockIdx.x >> 2, q = blockIdx.x & 3;
    int n0 = g * 16, m0 = q * 512;
    #pragma unroll
    for (int r = 0; r < 16; ++r) {
        T[r][tid] = adj[(size_t)(n0 + r) * Nn + m0 + tid];
        T[r][tid + 256] = adj[(size_t)(n0 + r) * Nn + m0 + tid + 256];
    }
    __syncthreads();
    unsigned short* region = adjF + ((size_t)g * 512 + q * 128) * 64;
    #pragma unroll
    for (int i = 0; i < 4; ++i) {
        int e0 = (i * 256 + tid) * 8;
        u16x8 w;
        #pragma unroll
        for (int j = 0; j < 8; ++j) {
            int e = e0 + j;
            int mq = e >> 6, nl = (e >> 2) & 15, mm = e & 3;
            w[j] = f2b(cg * T[nl][mq * 4 + mm]);
        }
        *(u16x8*)(region + e0) = w;
    }
}

// ---------- fused QKV + delayed-signal: Q prescaled by cs; K frag; V 48-row frag ----
// Kf[((b*128+(m>>4))*4+(k>>3))*16+(m&15)][8]        -> 65536 shorts/batch
// Vf[((b*64+(m>>5))*4+((m>>3)&3))*48 + h][8], h<48  -> 98304 shorts/batch
//   rows 0..31 = V^T, row 32 = delayed signal, row 33 = 1.0, rows 34..47 = 0
__global__ void k_qkv(const float* __restrict__ feat, const float* __restrict__ x,
                      const float* __restrict__ dlog,
                      const float* __restrict__ Wq, const float* __restrict__ bq,
                      const float* __restrict__ Wk, const float* __restrict__ bk,
                      const float* __restrict__ Wv, const float* __restrict__ bv,
                      const float* __restrict__ geo_w,
                      unsigned short* __restrict__ Qbf, unsigned short* __restrict__ Kf,
                      unsigned short* __restrict__ Vf) {
    __shared__ float WqT[Hh][Hh + 1], WkT[Hh][Hh + 1], WvT[Hh][Hh + 1];
    __shared__ float f[8][Hh];
    __shared__ __align__(16) unsigned short VT8[Hh][8];
    __shared__ __align__(16) unsigned short DS8[8];
    int tid = threadIdx.x;
    for (int i = tid; i < Hh * Hh; i += 256) {
        int h = i >> 5, k = i & 31;
        WqT[k][h] = Wq[i];
        WkT[k][h] = Wk[i];
        WvT[k][h] = Wv[i];
    }
    int n0 = blockIdx.x * 8;
    int b = n0 >> 11, mloc0 = n0 & 2047;
    // ---- delayed signal for this 8-row octet (wave 0 only) ----
    if (tid < 64) {
        float mx = -1e30f;
        #pragma unroll
        for (int t = 0; t < LAGS; ++t) mx = fmaxf(mx, dlog[t]);
        float s = 0.f, wv[LAGS];
        #pragma unroll
        for (int t = 0; t < LAGS; ++t) { wv[t] = __expf(dlog[t] - mx); s += wv[t]; }
        int t = tid >> 3, j = tid & 7;
        float dsv = (wv[t] / s) * x[(size_t)b * Tt * Nn + (size_t)(Tt - 1 - t) * Nn + mloc0 + j];
        dsv += __shfl_xor(dsv, 8);
        dsv += __shfl_xor(dsv, 16);
        dsv += __shfl_xor(dsv, 32);
        if (tid < 8) DS8[tid] = f2b(dsv);
    }
    float geo = 1.f / (1.f + __expf(-geo_w[0]));
    float cs = (1.f - geo) * 0.17677669529663687f;   // (1-geo)/sqrt(32)
    f[tid >> 5][tid & 31] = feat[(size_t)n0 * Hh + tid];
    __syncthreads();
    int lr = tid >> 5, h = tid & 31;
    float aq = bq[h], ak = bk[h], av = bv[h];
    #pragma unroll
    for (int k = 0; k < Hh; ++k) {
        float fv = f[lr][k];
        aq += fv * WqT[k][h];
        ak += fv * WkT[k][h];
        av += fv * WvT[k][h];
    }
    Qbf[(size_t)(n0 + lr) * Hh + h] = f2b(aq * cs);
    int mloc = mloc0 + lr;
    size_t kaddr = ((((size_t)b * 128 + (mloc >> 4)) * 4 + (h >> 3)) * 16 + (mloc & 15)) * 8 + (h & 7);
    Kf[kaddr] = f2b(ak);
    VT8[h][lr] = f2b(av);
    __syncthreads();
    size_t vbase = (((size_t)b * 64 + (mloc0 >> 5)) * 4 + ((mloc0 >> 3) & 3)) * 48;
    if (tid < 32) {
        *(u16x8*)(Vf + (vbase + tid) * 8) = *(const u16x8*)&VT8[tid][0];
    } else if (tid < 48) {
        int rr = tid - 32;            // 0=ds, 1=ones, 2..15=zero
        u16x8 wv8;
        if (rr == 0) {
            wv8 = *(const u16x8*)&DS8[0];
        } else {
            unsigned short fill = (rr == 1) ? (unsigned short)0x3F80 : (unsigned short)0;
            for (int j = 0; j < 8; ++j) wv8[j] = fill;
        }
        *(u16x8*)(Vf + (vbase + 32 + rr) * 8) = wv8;
    }
}

// ---------------- MFMA attention + fused output-proj + LayerNorm ------------------
// r21 base (best: 53.6 us) + s_setprio(1) around the MFMA clusters (T5): barrier-free
// loop means co-resident waves sit at different phases, the regime where setprio
// measured +4-7% on attention (m191). Everything else identical to r21.
__global__ __launch_bounds__(256, 2)
void k_attn(const unsigned short* __restrict__ Qbf,
            const unsigned short* __restrict__ Kf,
            const unsigned short* __restrict__ Vf,
            const unsigned short* __restrict__ adjF,
            const float* __restrict__ feat,
            const float* __restrict__ Wo, const float* __restrict__ bo,
            const float* __restrict__ gamma, const float* __restrict__ beta,
            float* __restrict__ out) {
    __shared__ __align__(16) unsigned short Pt[4][2][32 * PSTR];  // 28672 B; merge scratch later
    __shared__ float WoT[Hh][Hh + 1];
    __shared__ float combT[32][Hh + 1];
    __shared__ float gbb[3][Hh];

    int tid = threadIdx.x;
    int wid = tid >> 6, lane = tid & 63;
    int nl = lane & 15, g4 = lane >> 4;
    int wh = wid;

    for (int i = tid; i < Hh * Hh; i += 256) WoT[i & 31][i >> 5] = Wo[i];
    if (tid < 32) { gbb[0][tid] = bo[tid]; gbb[1][tid] = gamma[tid]; gbb[2][tid] = beta[tid]; }

    // XCD-partitioned swizzle: xcd = bid&7 -> (n-quarter = xcd>>1, batch-half = xcd&1)
    int bid = blockIdx.x;
    int xcd = bid & 7, r = bid >> 3;            // r: 0..127
    int b = ((xcd & 1) << 3) + (r & 7);
    int nt32 = ((xcd >> 1) << 4) + (r >> 3);    // 0..63
    int n0w = nt32 * 32;

    // Q B-fragments (col = n = nl, k = g4*8+j); Q pre-scaled by cs
    s8v qf[2];
    #pragma unroll
    for (int nt = 0; nt < 2; ++nt)
        qf[nt] = *(const s8v*)(Qbf + (((size_t)b * Nn + n0w + nt * 16 + nl) << 5) + g4 * 8);

    f4 pacc[2][3];
    #pragma unroll
    for (int nt = 0; nt < 2; ++nt)
        #pragma unroll
        for (int t = 0; t < 3; ++t) pacc[nt][t] = (f4){0.f, 0.f, 0.f, 0.f};

    const unsigned short* Kb = Kf + (size_t)b * 65536;
    const unsigned short* Vb = Vf + (size_t)b * 98304;
    unsigned short* Pw0 = Pt[wid][0];
    unsigned short* Pw1 = Pt[wid][1];

    // pointer-bump bases (chunk 0, this wave's 32-m window)
    const unsigned short* pK  = Kb + (((size_t)(wh * 2) * 4 + g4) * 16 + nl) * 8;
    const unsigned short* pV  = Vb + (((size_t)wh * 4 + g4) * 48 + nl) * 8;
    const unsigned short* pA0 = adjF + ((size_t)(nt32 * 2) * 512 + wh * 8 + g4) * 64 + nl * 4;
    const unsigned short* pA1 = adjF + ((size_t)(nt32 * 2 + 1) * 512 + wh * 8 + g4) * 64 + nl * 4;

    struct Frag {
        s8v kf0, kf1, vf0, vf1, vf2;
        u16x4 a00, a01, a10, a11;
    };

    auto loadP = [&](Frag& F) {
        F.kf0 = *(const s8v*)(pK);
        F.kf1 = *(const s8v*)(pK + 512);
        F.vf0 = *(const s8v*)(pV);
        F.vf1 = *(const s8v*)(pV + 128);
        F.vf2 = *(const s8v*)(pV + 256);
        F.a00 = *(const u16x4*)(pA0);
        F.a01 = *(const u16x4*)(pA0 + 256);
        F.a10 = *(const u16x4*)(pA1);
        F.a11 = *(const u16x4*)(pA1 + 256);
        pK += 4096;
        pV += 6144;
        pA0 += 2048;
        pA1 += 2048;
        __builtin_amdgcn_sched_barrier(0);   // pin load issue: no sinking past here
    };

    auto mkC = [&](u16x4 av) -> f4 {
        f4 C;
        C[0] = b2f(av[0]); C[1] = b2f(av[1]); C[2] = b2f(av[2]); C[3] = b2f(av[3]);
        return C;
    };

    auto SM = [&](f4 sc, int nt, int mg, unsigned short* Pw) {
        float p0 = __expf(sc[0]), p1 = __expf(sc[1]);
        float p2 = __expf(sc[2]), p3 = __expf(sc[3]);
        uint2 w;
        w.x = packbf2(p0, p1);
        w.y = packbf2(p2, p3);
        *(uint2*)(Pw + (size_t)(nt * 16 + nl) * PSTR + mg * 16 + g4 * 4) = w;
    };

    auto qks = [&](Frag& F, unsigned short* Pw) {
        __builtin_amdgcn_s_setprio(1);
        f4 sc00 = __builtin_amdgcn_mfma_f32_16x16x32_bf16(F.kf0, qf[0], mkC(F.a00), 0, 0, 0);
        f4 sc01 = __builtin_amdgcn_mfma_f32_16x16x32_bf16(F.kf1, qf[0], mkC(F.a01), 0, 0, 0);
        f4 sc10 = __builtin_amdgcn_mfma_f32_16x16x32_bf16(F.kf0, qf[1], mkC(F.a10), 0, 0, 0);
        f4 sc11 = __builtin_amdgcn_mfma_f32_16x16x32_bf16(F.kf1, qf[1], mkC(F.a11), 0, 0, 0);
        __builtin_amdgcn_s_setprio(0);
        SM(sc00, 0, 0, Pw);
        SM(sc01, 0, 1, Pw);
        SM(sc10, 1, 0, Pw);
        SM(sc11, 1, 1, Pw);
    };

    auto readP = [&](const unsigned short* Pw, s8v& pb0, s8v& pb1) {
        pb0 = *(const s8v*)(Pw + (size_t)(0 * 16 + nl) * PSTR + g4 * 8);
        pb1 = *(const s8v*)(Pw + (size_t)(1 * 16 + nl) * PSTR + g4 * 8);
    };

    auto pvm = [&](s8v v0, s8v v1, s8v v2, s8v pb0, s8v pb1) {
        __builtin_amdgcn_s_setprio(1);
        pacc[0][0] = __builtin_amdgcn_mfma_f32_16x16x32_bf16(v0, pb0, pacc[0][0], 0, 0, 0);
        pacc[0][1] = __builtin_amdgcn_mfma_f32_16x16x32_bf16(v1, pb0, pacc[0][1], 0, 0, 0);
        pacc[0][2] = __builtin_amdgcn_mfma_f32_16x16x32_bf16(v2, pb0, pacc[0][2], 0, 0, 0);
        pacc[1][0] = __builtin_amdgcn_mfma_f32_16x16x32_bf16(v0, pb1, pacc[1][0], 0, 0, 0);
        pacc[1][1] = __builtin_amdgcn_mfma_f32_16x16x32_bf16(v1, pb1, pacc[1][1], 0, 0, 0);
        pacc[1][2] = __builtin_amdgcn_mfma_f32_16x16x32_bf16(v2, pb1, pacc[1][2], 0, 0, 0);
        __builtin_amdgcn_s_setprio(0);
    };

    const int NC = Nn / 128;     // 16
    Frag A, B;
    s8v sv0, sv1, sv2, pb0, pb1;

    loadP(A);                    // chunk 0
    loadP(B);                    // chunk 1 (in flight)
    qks(A, Pw0);                 // QK+SM chunk 0 -> P0
    sv0 = A.vf0; sv1 = A.vf1; sv2 = A.vf2;

    for (int i = 0; i < (NC - 2) / 2; ++i) {   // i = 0..6 : chunks 2i+1, 2i+2
        readP(Pw0, pb0, pb1);    // P(2i)  — written a full stage ago
        loadP(A);                // chunk 2i+2 (pinned issue)
        qks(B, Pw1);             // QK+SM chunk 2i+1 -> P(2i+1)
        pvm(sv0, sv1, sv2, pb0, pb1);          // PV chunk 2i
        sv0 = B.vf0; sv1 = B.vf1; sv2 = B.vf2;
        loadP(B);                // chunk 2i+3 (pinned issue)
        readP(Pw1, pb0, pb1);    // P(2i+1)
        qks(A, Pw0);             // QK+SM chunk 2i+2 -> P(2i+2)
        pvm(sv0, sv1, sv2, pb0, pb1);          // PV chunk 2i+1
        sv0 = A.vf0; sv1 = A.vf1; sv2 = A.vf2;
    }
    // epilogue: chunks NC-2 (in A, P in Pw0) and NC-1 (in B)
    readP(Pw0, pb0, pb1);        // P(NC-2)
    qks(B, Pw1);                 // QK+SM chunk NC-1 -> P(NC-1)
    pvm(sv0, sv1, sv2, pb0, pb1);              // PV chunk NC-2
    sv0 = B.vf0; sv1 = B.vf1; sv2 = B.vf2;
    readP(Pw1, pb0, pb1);        // P(NC-1)
    pvm(sv0, sv1, sv2, pb0, pb1);              // PV chunk NC-1

    // ---- linear merge of pacc (24 floats/lane) across the 4 wh waves ----
    float* mrgb = (float*)&Pt[0][0][0];   // 2 regions x 64 lanes x 24 floats = 12288 B <= 28672
    __syncthreads();                      // all PV reads of Pt done
    if (wh & 1) {
        float* d = mrgb + ((size_t)(wh >> 1) * 64 + lane) * 24;
        #pragma unroll
        for (int nt = 0; nt < 2; ++nt)
            #pragma unroll
            for (int t = 0; t < 3; ++t)
                #pragma unroll
                for (int r2 = 0; r2 < 4; ++r2) d[(nt * 3 + t) * 4 + r2] = pacc[nt][t][r2];
    }
    __syncthreads();
    if (!(wh & 1)) {
        const float* d = mrgb + ((size_t)(wh >> 1) * 64 + lane) * 24;
        #pragma unroll
        for (int nt = 0; nt < 2; ++nt)
            #pragma unroll
            for (int t = 0; t < 3; ++t)
                #pragma unroll
                for (int r2 = 0; r2 < 4; ++r2) pacc[nt][t][r2] += d[(nt * 3 + t) * 4 + r2];
    }
    __syncthreads();
    if (wh == 2) {
        float* d = mrgb + (size_t)lane * 24;
        #pragma unroll
        for (int nt = 0; nt < 2; ++nt)
            #pragma unroll
            for (int t = 0; t < 3; ++t)
                #pragma unroll
                for (int r2 = 0; r2 < 4; ++r2) d[(nt * 3 + t) * 4 + r2] = pacc[nt][t][r2];
    }
    __syncthreads();
    if (wh == 0) {
        const float* d = mrgb + (size_t)lane * 24;
        #pragma unroll
        for (int nt = 0; nt < 2; ++nt)
            #pragma unroll
            for (int t = 0; t < 3; ++t)
                #pragma unroll
                for (int r2 = 0; r2 < 4; ++r2) pacc[nt][t][r2] += d[(nt * 3 + t) * 4 + r2];

        // comb = feat + attended/ps + 0.1*prop/ps  -> combT (LDS)
        #pragma unroll
        for (int nt = 0; nt < 2; ++nt) {
            float psn = __shfl(pacc[nt][2][1], nl);   // ones-row (h=33): g4==0, reg 1
            float prn = __shfl(pacc[nt][2][0], nl);   // ds-row   (h=32): g4==0, reg 0
            float invS = 1.f / psn;
            float pp = prn * invS * 0.1f;
            size_t o = ((size_t)b * Nn + n0w + nt * 16 + nl) * Hh;
            #pragma unroll
            for (int t = 0; t < 2; ++t) {
                f4 fv = *(const f4*)(feat + o + t * 16 + g4 * 4);
                #pragma unroll
                for (int r2 = 0; r2 < 4; ++r2)
                    combT[nt * 16 + nl][t * 16 + g4 * 4 + r2] = fv[r2] + pacc[nt][t][r2] * invS + pp;
            }
        }
    }
    __syncthreads();

    // ---- fused output projection + LayerNorm (each wave: 8 rows) ----
    int h = lane & 31;
    #pragma unroll
    for (int pass = 0; pass < 4; ++pass) {
        int row = wh * 8 + pass * 2 + (lane >> 5);
        float a = gbb[0][h];
        #pragma unroll
        for (int k = 0; k < Hh; ++k) a += combT[row][k] * WoT[k][h];
        float mu = a;
        #pragma unroll
        for (int w = 1; w < 32; w <<= 1) mu += __shfl_xor(mu, w);
        mu *= (1.f / 32.f);
        float dd = a - mu;
        float v = dd * dd;
        #pragma unroll
        for (int w = 1; w < 32; w <<= 1) v += __shfl_xor(v, w);
        v *= (1.f / 32.f);
        out[((size_t)b * Nn + n0w + row) * Hh + h] =
            dd * rsqrtf(v + LN_EPS) * gbb[1][h] + gbb[2][h];
    }
}

extern "C" void kernel_launch(void* const* d_in, const int* in_sizes, int n_in,
                              void* d_out, int out_size, void* d_ws, size_t ws_size,
                              hipStream_t stream) {
    const float* x     = (const float*)d_in[0];
    const float* feat  = (const float*)d_in[1];
    const float* dlog  = (const float*)d_in[2];
    const float* Wq    = (const float*)d_in[3];
    const float* bq    = (const float*)d_in[4];
    const float* Wk    = (const float*)d_in[5];
    const float* bk    = (const float*)d_in[6];
    const float* Wv    = (const float*)d_in[7];
    const float* bv    = (const float*)d_in[8];
    const float* adj   = (const float*)d_in[9];
    const float* geo   = (const float*)d_in[10];
    const float* Wo    = (const float*)d_in[11];
    const float* bo    = (const float*)d_in[12];
    const float* gamma = (const float*)d_in[13];
    const float* beta  = (const float*)d_in[14];
    float* out = (float*)d_out;

    char* w = (char*)d_ws;
    unsigned short* Qbf  = (unsigned short*)w;  w += (size_t)Bb * Nn * Hh * 2;
    unsigned short* Kf   = (unsigned short*)w;  w += (size_t)Bb * Nn * Hh * 2;
    unsigned short* Vf   = (unsigned short*)w;  w += (size_t)Bb * 98304 * 2;   // 48-row frag
    unsigned short* adjF = (unsigned short*)w;  w += (size_t)Nn * Nn * 2;

    k_adjprep<<<512, 256, 0, stream>>>(adj, geo, adjF);
    k_qkv<<<Bb * Nn / 8, 256, 0, stream>>>(feat, x, dlog, Wq, bq, Wk, bk, Wv, bv, geo,
                                           Qbf, Kf, Vf);
    k_attn<<<1024, 256, 0, stream>>>(Qbf, Kf, Vf, adjF, feat, Wo, bo, gamma, beta, out);
}